// Round 2
// baseline (3316.064 us; speedup 1.0000x reference)
//
#include <hip/hip_runtime.h>
#include <math.h>

#define Bsz 64
#define Nn  512
#define Dd  128
#define NITER 100

// ---------------- ws layout (bytes) ----------------
// K  : [64][512][512] f32 @ 0            (67108864)
// M  : [64][512][512] f32 @ 67108864     (67108864)
// sq1: [64][512] f32 @ 134217728
// sq2: [64][512] f32 @ 134348800
// rowmin: [64][512] f32-bits @ 134479872
// maxm  : [64] f32-bits @ 134610944
// acc   : double @ 134611200

// ---------------- init (ws is poisoned 0xAA every call) ----------------
__global__ void k_init(unsigned* __restrict__ rowmin, unsigned* __restrict__ maxm,
                       double* __restrict__ acc) {
    int t = blockIdx.x * blockDim.x + threadIdx.x;
    if (t < Bsz * Nn) rowmin[t] = 0x7F800000u;  // +inf
    if (t < Bsz) maxm[t] = 0u;
    if (t == 0) *acc = 0.0;
}

// ---------------- row squared norms ----------------
__global__ void k_norms(const float* __restrict__ x1, const float* __restrict__ x2,
                        float* __restrict__ sq1, float* __restrict__ sq2) {
    int gw = (blockIdx.x * blockDim.x + threadIdx.x) >> 6;  // global wave id
    int l = threadIdx.x & 63;
    bool first = gw < Bsz * Nn;
    int row = first ? gw : gw - Bsz * Nn;
    const float* src = first ? x1 : x2;
    float a = src[(size_t)row * Dd + l];
    float c = src[(size_t)row * Dd + 64 + l];
    float s = a * a + c * c;
    #pragma unroll
    for (int m = 32; m >= 1; m >>= 1) s += __shfl_xor(s, m);
    if (l == 0) (first ? sq1 : sq2)[row] = s;
}

// ---------------- M = pairwise distances + per-row min + per-batch max ----------------
__global__ __launch_bounds__(256) void k_gemm(
        const float* __restrict__ x1, const float* __restrict__ x2,
        const float* __restrict__ sq1, const float* __restrict__ sq2,
        float* __restrict__ M, unsigned* __restrict__ rowmin,
        unsigned* __restrict__ maxm) {
    __shared__ float As[64][129];
    __shared__ float Bs[64][129];
    __shared__ float redmin[64][16];
    __shared__ float wmax[4];
    const int b = blockIdx.z;
    const int i0 = blockIdx.y * 64, j0 = blockIdx.x * 64;
    const int tx = threadIdx.x, ty = threadIdx.y;
    const int tid = ty * 16 + tx;

    const float4* a4 = (const float4*)(x1 + ((size_t)b * Nn + i0) * Dd);
    const float4* b4 = (const float4*)(x2 + ((size_t)b * Nn + j0) * Dd);
    #pragma unroll
    for (int e = 0; e < 8; e++) {
        int idx = tid + e * 256;          // 0..2047 float4s
        int r = idx >> 5, c = idx & 31;
        float4 va = a4[(size_t)r * 32 + c];
        float4 vb = b4[(size_t)r * 32 + c];
        As[r][c*4+0] = va.x; As[r][c*4+1] = va.y; As[r][c*4+2] = va.z; As[r][c*4+3] = va.w;
        Bs[r][c*4+0] = vb.x; Bs[r][c*4+1] = vb.y; Bs[r][c*4+2] = vb.z; Bs[r][c*4+3] = vb.w;
    }
    __syncthreads();

    float acc[4][4] = {{0.0f}};
    for (int k = 0; k < Dd; k++) {
        float av[4], bv[4];
        #pragma unroll
        for (int e = 0; e < 4; e++) av[e] = As[ty*4+e][k];
        #pragma unroll
        for (int f = 0; f < 4; f++) bv[f] = Bs[tx*4+f][k];
        #pragma unroll
        for (int e = 0; e < 4; e++)
            #pragma unroll
            for (int f = 0; f < 4; f++)
                acc[e][f] += av[e] * bv[f];
    }

    float lmax = 0.0f;
    #pragma unroll
    for (int e = 0; e < 4; e++) {
        const int i = i0 + ty*4 + e;
        const float s1 = sq1[b*Nn + i];
        float lmin = 3.0e38f;
        float mvv[4];
        #pragma unroll
        for (int f = 0; f < 4; f++) {
            const int j = j0 + tx*4 + f;
            float d2 = s1 + sq2[b*Nn + j] - 2.0f * acc[e][f];
            float m = sqrtf(fmaxf(d2, 0.0f));
            mvv[f] = m;
            lmin = fminf(lmin, m);
            lmax = fmaxf(lmax, m);
        }
        float4 mv; mv.x = mvv[0]; mv.y = mvv[1]; mv.z = mvv[2]; mv.w = mvv[3];
        *(float4*)(M + ((size_t)b * Nn + i) * Nn + j0 + tx*4) = mv;
        redmin[ty*4+e][tx] = lmin;
    }
    #pragma unroll
    for (int m = 32; m >= 1; m >>= 1) lmax = fmaxf(lmax, __shfl_xor(lmax, m));
    if ((tid & 63) == 0) wmax[tid >> 6] = lmax;
    __syncthreads();
    if (tid < 64) {
        float mn = redmin[tid][0];
        #pragma unroll
        for (int q = 1; q < 16; q++) mn = fminf(mn, redmin[tid][q]);
        atomicMin(&rowmin[b*Nn + i0 + tid], __float_as_uint(mn));
    }
    if (tid == 0) {
        float mm = fmaxf(fmaxf(wmax[0], wmax[1]), fmaxf(wmax[2], wmax[3]));
        atomicMax(&maxm[b], __float_as_uint(mm));
    }
}

// ---------------- K' = exp(-(M - rowmin_i) * s_b), fp32, row-stabilized ----------------
__global__ void k_expk(const float* __restrict__ M, const float* __restrict__ rowmin,
                       const float* __restrict__ maxm, float* __restrict__ K) {
    size_t q = (size_t)blockIdx.x * blockDim.x + threadIdx.x;  // float4 index
    size_t base = q * 4;
    int b = (int)(base >> 18);           // / (512*512)
    int i = (int)((base >> 9) & 511);
    float s = 1.0f / (0.01f * maxm[b]);  // 1/(reg * maxM_b)
    float rm = rowmin[(size_t)b * Nn + i];
    float4 m = *(const float4*)(M + base);
    float4 k;
    k.x = expf(-(m.x - rm) * s);
    k.y = expf(-(m.y - rm) * s);
    k.z = expf(-(m.z - rm) * s);
    k.w = expf(-(m.w - rm) * s);
    *(float4*)(K + base) = k;
}

// ---------------- persistent Sinkhorn: one block per batch ----------------
__global__ __launch_bounds__(1024) void k_sink(
        const float* __restrict__ Kg, const float* __restrict__ Mg,
        const float* __restrict__ rowmin, const float* __restrict__ maxm,
        double* __restrict__ acc) {
    __shared__ float red[16][512];
    __shared__ float u[512];
    __shared__ float v[512];
    __shared__ float wred[16];
    __shared__ double wsumd[16];
    __shared__ float rminsh;

    const int b = blockIdx.x;
    const int t = threadIdx.x;
    const int w = t >> 6, l = t & 63;
    const float* __restrict__ K = Kg + (size_t)b * Nn * Nn;
    const float* __restrict__ M = Mg + (size_t)b * Nn * Nn;
    const float s = 1.0f / (0.01f * maxm[b]);

    // per-batch min of rowmin (for centering u0 into fp32 range)
    float rv = (t < Nn) ? rowmin[(size_t)b * Nn + t] : 3.0e38f;
    float rmw = rv;
    #pragma unroll
    for (int m = 32; m >= 1; m >>= 1) rmw = fminf(rmw, __shfl_xor(rmw, m));
    if (l == 0) wred[w] = rmw;
    __syncthreads();
    if (t == 0) {
        float q = wred[0];
        for (int i = 1; i < 16; i++) q = fminf(q, wred[i]);
        rminsh = q;
    }
    __syncthreads();
    // u0' = exp(-(rowmin_i - rmin_b)*s)/512  (scaled-space start, exact correspondence)
    if (t < Nn) u[t] = expf(-(rv - rminsh) * s) * (1.0f / 512.0f);
    __syncthreads();

    for (int it = 0; it < NITER; it++) {
        // ---- KtU_j = sum_i K[i][j]*u[i] : per-wave register partials over strided rows
        float a0=0,a1=0,a2=0,a3=0,b0=0,b1=0,b2=0,b3=0;
        for (int i = w; i < Nn; i += 16) {
            const float ui = u[i];
            const float4 k0 = *(const float4*)(K + (size_t)i * Nn + 4*l);
            const float4 k1 = *(const float4*)(K + (size_t)i * Nn + 256 + 4*l);
            a0 += k0.x * ui; a1 += k0.y * ui; a2 += k0.z * ui; a3 += k0.w * ui;
            b0 += k1.x * ui; b1 += k1.y * ui; b2 += k1.z * ui; b3 += k1.w * ui;
        }
        *(float4*)&red[w][4*l]       = make_float4(a0,a1,a2,a3);
        *(float4*)&red[w][256 + 4*l] = make_float4(b0,b1,b2,b3);
        __syncthreads();
        if (t < Nn) {
            float kt = 0.0f;
            #pragma unroll
            for (int q = 0; q < 16; q++) kt += red[q][t];
            v[t] = (1.0f / 512.0f) / kt;
        }
        __syncthreads();
        // ---- KV_i = sum_j K[i][j]*v[j] : row dot + wave reduce
        for (int i = w; i < Nn; i += 16) {
            const float4 k0 = *(const float4*)(K + (size_t)i * Nn + 4*l);
            const float4 k1 = *(const float4*)(K + (size_t)i * Nn + 256 + 4*l);
            const float4 v0 = *(const float4*)(v + 4*l);
            const float4 v1 = *(const float4*)(v + 256 + 4*l);
            float sr = k0.x*v0.x + k0.y*v0.y + k0.z*v0.z + k0.w*v0.w
                     + k1.x*v1.x + k1.y*v1.y + k1.z*v1.z + k1.w*v1.w;
            #pragma unroll
            for (int m = 32; m >= 1; m >>= 1) sr += __shfl_xor(sr, m);
            if (l == 0) u[i] = (1.0f / 512.0f) / sr;
        }
        __syncthreads();
    }

    // ---- total += sum_ij M_ij * u_i * K'_ij * v_j  (== M·P exactly in scaled space)
    double ls = 0.0;
    for (int i = w; i < Nn; i += 16) {
        const float ui = u[i];
        const float4 k0 = *(const float4*)(K + (size_t)i * Nn + 4*l);
        const float4 k1 = *(const float4*)(K + (size_t)i * Nn + 256 + 4*l);
        const float4 m0 = *(const float4*)(M + (size_t)i * Nn + 4*l);
        const float4 m1 = *(const float4*)(M + (size_t)i * Nn + 256 + 4*l);
        const float4 v0 = *(const float4*)(v + 4*l);
        const float4 v1 = *(const float4*)(v + 256 + 4*l);
        float p = m0.x*k0.x*v0.x + m0.y*k0.y*v0.y + m0.z*k0.z*v0.z + m0.w*k0.w*v0.w
                + m1.x*k1.x*v1.x + m1.y*k1.y*v1.y + m1.z*k1.z*v1.z + m1.w*k1.w*v1.w;
        ls += (double)(p * ui);
    }
    #pragma unroll
    for (int m = 32; m >= 1; m >>= 1) ls += __shfl_xor(ls, m);
    if (l == 0) wsumd[w] = ls;
    __syncthreads();
    if (t == 0) {
        double tot = 0.0;
        for (int q = 0; q < 16; q++) tot += wsumd[q];
        atomicAdd(acc, tot);
    }
}

__global__ void k_final(const double* __restrict__ acc, float* __restrict__ out) {
    out[0] = (float)acc[0];
}

extern "C" void kernel_launch(void* const* d_in, const int* in_sizes, int n_in,
                              void* d_out, int out_size, void* d_ws, size_t ws_size,
                              hipStream_t stream) {
    const float* x1 = (const float*)d_in[0];
    const float* x2 = (const float*)d_in[1];
    float* out = (float*)d_out;
    char* ws = (char*)d_ws;

    float*  K      = (float*)(ws);
    float*  M      = (float*)(ws + 67108864);
    float*  sq1    = (float*)(ws + 134217728);
    float*  sq2    = (float*)(ws + 134348800);
    float*  rowmin = (float*)(ws + 134479872);
    float*  maxm   = (float*)(ws + 134610944);
    double* acc    = (double*)(ws + 134611200);

    hipLaunchKernelGGL(k_init, dim3(128), dim3(256), 0, stream,
                       (unsigned*)rowmin, (unsigned*)maxm, acc);
    hipLaunchKernelGGL(k_norms, dim3(16384), dim3(256), 0, stream, x1, x2, sq1, sq2);
    hipLaunchKernelGGL(k_gemm, dim3(8, 8, 64), dim3(16, 16), 0, stream,
                       x1, x2, sq1, sq2, M, (unsigned*)rowmin, (unsigned*)maxm);
    hipLaunchKernelGGL(k_expk, dim3(16384), dim3(256), 0, stream, M, rowmin, maxm, K);
    hipLaunchKernelGGL(k_sink, dim3(64), dim3(1024), 0, stream, K, M, rowmin, maxm, acc);
    hipLaunchKernelGGL(k_final, dim3(1), dim3(1), 0, stream, acc, out);
}

// Round 3
// 1142.449 us; speedup vs baseline: 2.9026x; 2.9026x over previous
//
#include <hip/hip_runtime.h>
#include <math.h>

#define Bsz 64
#define Nn  512
#define Dd  128
#define NITER 100
#define SLICES 4
#define ROWS 128   // Nn/SLICES

// ---------------- ws layout (bytes) ----------------
// M       : [64][512][512] f32 @ 0          (67108864)
// partials: [64][2][4][512] f32 @ 67108864  (1048576)   parity-double-buffered
// bar     : [64][32] u32 @ 68157440         (8192)      one counter per 128B
// sq1     : [64][512] f32 @ 68165632        (131072)
// sq2     : [64][512] f32 @ 68296704        (131072)
// rowmin  : [64][512] f32-bits @ 68427776   (131072)
// maxm    : [64] f32-bits @ 68558848        (256)
// acc     : double @ 68559104               (8)

__device__ inline float blo(unsigned x) { return __uint_as_float(x << 16); }
__device__ inline float bhi(unsigned x) { return __uint_as_float(x & 0xffff0000u); }
__device__ inline unsigned short bf16rne(float f) {
    unsigned u = __float_as_uint(f);
    u += 0x7fffu + ((u >> 16) & 1u);
    return (unsigned short)(u >> 16);
}

// ---------------- init (ws is poisoned 0xAA every call) ----------------
__global__ void k_init(unsigned* __restrict__ rowmin, unsigned* __restrict__ maxm,
                       unsigned* __restrict__ bar, double* __restrict__ acc) {
    int t = blockIdx.x * blockDim.x + threadIdx.x;
    if (t < Bsz * Nn) rowmin[t] = 0x7F800000u;  // +inf
    if (t < Bsz) maxm[t] = 0u;
    if (t < Bsz * 32) bar[t] = 0u;
    if (t == 0) *acc = 0.0;
}

// ---------------- row squared norms ----------------
__global__ void k_norms(const float* __restrict__ x1, const float* __restrict__ x2,
                        float* __restrict__ sq1, float* __restrict__ sq2) {
    int gw = (blockIdx.x * blockDim.x + threadIdx.x) >> 6;  // global wave id
    int l = threadIdx.x & 63;
    bool first = gw < Bsz * Nn;
    int row = first ? gw : gw - Bsz * Nn;
    const float* src = first ? x1 : x2;
    float a = src[(size_t)row * Dd + l];
    float c = src[(size_t)row * Dd + 64 + l];
    float s = a * a + c * c;
    #pragma unroll
    for (int m = 32; m >= 1; m >>= 1) s += __shfl_xor(s, m);
    if (l == 0) (first ? sq1 : sq2)[row] = s;
}

// ---------------- M = pairwise distances + per-row min + per-batch max ----------------
__global__ __launch_bounds__(256) void k_gemm(
        const float* __restrict__ x1, const float* __restrict__ x2,
        const float* __restrict__ sq1, const float* __restrict__ sq2,
        float* __restrict__ M, unsigned* __restrict__ rowmin,
        unsigned* __restrict__ maxm) {
    __shared__ float As[64][129];
    __shared__ float Bs[64][129];
    __shared__ float redmin[64][16];
    __shared__ float wmax[4];
    const int b = blockIdx.z;
    const int i0 = blockIdx.y * 64, j0 = blockIdx.x * 64;
    const int tx = threadIdx.x, ty = threadIdx.y;
    const int tid = ty * 16 + tx;

    const float4* a4 = (const float4*)(x1 + ((size_t)b * Nn + i0) * Dd);
    const float4* b4 = (const float4*)(x2 + ((size_t)b * Nn + j0) * Dd);
    #pragma unroll
    for (int e = 0; e < 8; e++) {
        int idx = tid + e * 256;          // 0..2047 float4s
        int r = idx >> 5, c = idx & 31;
        float4 va = a4[(size_t)r * 32 + c];
        float4 vb = b4[(size_t)r * 32 + c];
        As[r][c*4+0] = va.x; As[r][c*4+1] = va.y; As[r][c*4+2] = va.z; As[r][c*4+3] = va.w;
        Bs[r][c*4+0] = vb.x; Bs[r][c*4+1] = vb.y; Bs[r][c*4+2] = vb.z; Bs[r][c*4+3] = vb.w;
    }
    __syncthreads();

    float acc[4][4] = {{0.0f}};
    for (int k = 0; k < Dd; k++) {
        float av[4], bv[4];
        #pragma unroll
        for (int e = 0; e < 4; e++) av[e] = As[ty*4+e][k];
        #pragma unroll
        for (int f = 0; f < 4; f++) bv[f] = Bs[tx*4+f][k];
        #pragma unroll
        for (int e = 0; e < 4; e++)
            #pragma unroll
            for (int f = 0; f < 4; f++)
                acc[e][f] += av[e] * bv[f];
    }

    float lmax = 0.0f;
    #pragma unroll
    for (int e = 0; e < 4; e++) {
        const int i = i0 + ty*4 + e;
        const float s1 = sq1[b*Nn + i];
        float lmin = 3.0e38f;
        float mvv[4];
        #pragma unroll
        for (int f = 0; f < 4; f++) {
            const int j = j0 + tx*4 + f;
            float d2 = s1 + sq2[b*Nn + j] - 2.0f * acc[e][f];
            float m = sqrtf(fmaxf(d2, 0.0f));
            mvv[f] = m;
            lmin = fminf(lmin, m);
            lmax = fmaxf(lmax, m);
        }
        float4 mv; mv.x = mvv[0]; mv.y = mvv[1]; mv.z = mvv[2]; mv.w = mvv[3];
        *(float4*)(M + ((size_t)b * Nn + i) * Nn + j0 + tx*4) = mv;
        redmin[ty*4+e][tx] = lmin;
    }
    #pragma unroll
    for (int m = 32; m >= 1; m >>= 1) lmax = fmaxf(lmax, __shfl_xor(lmax, m));
    if ((tid & 63) == 0) wmax[tid >> 6] = lmax;
    __syncthreads();
    if (tid < 64) {
        float mn = redmin[tid][0];
        #pragma unroll
        for (int q = 1; q < 16; q++) mn = fminf(mn, redmin[tid][q]);
        atomicMin(&rowmin[b*Nn + i0 + tid], __float_as_uint(mn));
    }
    if (tid == 0) {
        float mm = fmaxf(fmaxf(wmax[0], wmax[1]), fmaxf(wmax[2], wmax[3]));
        atomicMax(&maxm[b], __float_as_uint(mm));
    }
}

// ---------------- persistent Sinkhorn: 4 blocks per batch, K' slice in LDS ----------------
__global__ __launch_bounds__(512) void k_sink(
        const float* __restrict__ Mg, const float* __restrict__ rowmin_f,
        const float* __restrict__ maxm, float* __restrict__ partials,
        unsigned* __restrict__ bar, double* __restrict__ acc) {
    __shared__ __align__(16) unsigned short Ks[ROWS][Nn];  // 131072 B, bf16 bits
    __shared__ float red8[8][Nn];                          // 16384 B
    __shared__ float vsh[Nn];                              // 2048 B
    __shared__ float ush[ROWS];                            // 512 B
    __shared__ float rml[ROWS];                            // 512 B
    __shared__ float sred[8];
    __shared__ double dred[8];

    const int blk = blockIdx.x;
    const int b  = blk >> 2;       // batch
    const int sl = blk & 3;        // row-slice
    const int r0 = sl * ROWS;
    const int t  = threadIdx.x;    // 0..511
    const int w  = t >> 6, l = t & 63;
    const float* __restrict__ Mb = Mg + ((size_t)b * Nn + r0) * Nn;
    const float sc = 1.0f / (0.01f * maxm[b]);
    float* part = partials + (size_t)b * (2 * SLICES * Nn);
    unsigned* mybar = bar + b * 32;

    // batch-wide min of rowmin (for u0 centering) + local rowmin slice to LDS
    float rv = rowmin_f[b * Nn + t];
    if (t < ROWS) rml[t] = rowmin_f[b * Nn + r0 + t];
    float rm = rv;
    #pragma unroll
    for (int m = 32; m >= 1; m >>= 1) rm = fminf(rm, __shfl_xor(rm, m));
    if (l == 0) sred[w] = rm;
    __syncthreads();
    const float rminb = fminf(fminf(fminf(sred[0],sred[1]), fminf(sred[2],sred[3])),
                              fminf(fminf(sred[4],sred[5]), fminf(sred[6],sred[7])));
    if (t < ROWS) ush[t] = __expf(-(rml[t] - rminb) * sc) * (1.0f / 512.0f);

    // fill Ks = bf16(exp(-(M - rowmin_row)*sc)) from M slice, coalesced float4
    for (int e = 0; e < 32; ++e) {
        int chunk = e * 512 + t;            // 0..16383 float4-chunks
        int row = chunk >> 7;
        int c4  = (chunk & 127) * 4;
        float4 m4 = *(const float4*)(Mb + (size_t)row * Nn + c4);
        float rmr = rml[row];
        ushort4 pk;
        pk.x = bf16rne(__expf(-(m4.x - rmr) * sc));
        pk.y = bf16rne(__expf(-(m4.y - rmr) * sc));
        pk.z = bf16rne(__expf(-(m4.z - rmr) * sc));
        pk.w = bf16rne(__expf(-(m4.w - rmr) * sc));
        *(ushort4*)&Ks[row][c4] = pk;
    }
    __syncthreads();

    int par = 0;
    for (int it = 0; it < NITER; ++it) {
        // ---- KtU partials: lane owns cols 8l..8l+7, wave owns rows w,w+8,...
        float a0=0,a1=0,a2=0,a3=0,a4=0,a5=0,a6=0,a7=0;
        for (int i = w; i < ROWS; i += 8) {
            const float ui = ush[i];
            const uint4 kb = *(const uint4*)&Ks[i][l * 8];
            a0 += blo(kb.x) * ui; a1 += bhi(kb.x) * ui;
            a2 += blo(kb.y) * ui; a3 += bhi(kb.y) * ui;
            a4 += blo(kb.z) * ui; a5 += bhi(kb.z) * ui;
            a6 += blo(kb.w) * ui; a7 += bhi(kb.w) * ui;
        }
        *(float4*)&red8[w][l*8]     = make_float4(a0, a1, a2, a3);
        *(float4*)&red8[w][l*8 + 4] = make_float4(a4, a5, a6, a7);
        __syncthreads();
        {
            float colsum = red8[0][t] + red8[1][t] + red8[2][t] + red8[3][t]
                         + red8[4][t] + red8[5][t] + red8[6][t] + red8[7][t];
            __hip_atomic_store(&part[par * (SLICES * Nn) + sl * Nn + t], colsum,
                               __ATOMIC_RELAXED, __HIP_MEMORY_SCOPE_AGENT);
        }
        __syncthreads();  // drains vmcnt: all partial stores complete before signal
        if (t == 0) {
            __hip_atomic_fetch_add(mybar, 1u, __ATOMIC_ACQ_REL, __HIP_MEMORY_SCOPE_AGENT);
            const unsigned tgt = (unsigned)(SLICES * (it + 1));
            while (__hip_atomic_load(mybar, __ATOMIC_ACQUIRE, __HIP_MEMORY_SCOPE_AGENT) < tgt)
                __builtin_amdgcn_s_sleep(1);
        }
        __syncthreads();
        {
            const float* pp = part + par * (SLICES * Nn);
            float s0 = __hip_atomic_load(&pp[0*Nn + t], __ATOMIC_RELAXED, __HIP_MEMORY_SCOPE_AGENT);
            float s1 = __hip_atomic_load(&pp[1*Nn + t], __ATOMIC_RELAXED, __HIP_MEMORY_SCOPE_AGENT);
            float s2 = __hip_atomic_load(&pp[2*Nn + t], __ATOMIC_RELAXED, __HIP_MEMORY_SCOPE_AGENT);
            float s3 = __hip_atomic_load(&pp[3*Nn + t], __ATOMIC_RELAXED, __HIP_MEMORY_SCOPE_AGENT);
            vsh[t] = (1.0f / 512.0f) / (s0 + s1 + s2 + s3);
        }
        __syncthreads();
        // ---- KV over local rows with v in registers
        const float4 va  = *(const float4*)&vsh[l * 8];
        const float4 vb4 = *(const float4*)&vsh[l * 8 + 4];
        for (int i = w; i < ROWS; i += 8) {
            const uint4 kb = *(const uint4*)&Ks[i][l * 8];
            float d = blo(kb.x)*va.x  + bhi(kb.x)*va.y  + blo(kb.y)*va.z  + bhi(kb.y)*va.w
                    + blo(kb.z)*vb4.x + bhi(kb.z)*vb4.y + blo(kb.w)*vb4.z + bhi(kb.w)*vb4.w;
            #pragma unroll
            for (int m = 32; m >= 1; m >>= 1) d += __shfl_xor(d, m);
            if (l == 0) ush[i] = (1.0f / 512.0f) / d;
        }
        __syncthreads();
        par ^= 1;
    }

    // ---- cost: sum over local rows of u_i * sum_j M_ij K'_ij v_j
    double lacc = 0.0;
    {
        const float4 va  = *(const float4*)&vsh[l * 8];
        const float4 vb4 = *(const float4*)&vsh[l * 8 + 4];
        for (int i = w; i < ROWS; i += 8) {
            const float ui = ush[i];
            const uint4 kb = *(const uint4*)&Ks[i][l * 8];
            const float4 ma  = *(const float4*)(Mb + (size_t)i * Nn + l * 8);
            const float4 mb4 = *(const float4*)(Mb + (size_t)i * Nn + l * 8 + 4);
            float p = ma.x*blo(kb.x)*va.x  + ma.y*bhi(kb.x)*va.y
                    + ma.z*blo(kb.y)*va.z  + ma.w*bhi(kb.y)*va.w
                    + mb4.x*blo(kb.z)*vb4.x + mb4.y*bhi(kb.z)*vb4.y
                    + mb4.z*blo(kb.w)*vb4.z + mb4.w*bhi(kb.w)*vb4.w;
            lacc += (double)(p * ui);
        }
    }
    #pragma unroll
    for (int m = 32; m >= 1; m >>= 1) lacc += __shfl_xor(lacc, m);
    if (l == 0) dred[w] = lacc;
    __syncthreads();
    if (t == 0) {
        double tot = dred[0]+dred[1]+dred[2]+dred[3]+dred[4]+dred[5]+dred[6]+dred[7];
        atomicAdd(acc, tot);
    }
}

__global__ void k_final(const double* __restrict__ acc, float* __restrict__ out) {
    out[0] = (float)acc[0];
}

extern "C" void kernel_launch(void* const* d_in, const int* in_sizes, int n_in,
                              void* d_out, int out_size, void* d_ws, size_t ws_size,
                              hipStream_t stream) {
    const float* x1 = (const float*)d_in[0];
    const float* x2 = (const float*)d_in[1];
    float* out = (float*)d_out;
    char* ws = (char*)d_ws;

    float*    M      = (float*)(ws);
    float*    part   = (float*)(ws + 67108864);
    unsigned* bar    = (unsigned*)(ws + 68157440);
    float*    sq1    = (float*)(ws + 68165632);
    float*    sq2    = (float*)(ws + 68296704);
    float*    rowmin = (float*)(ws + 68427776);
    float*    maxm   = (float*)(ws + 68558848);
    double*   acc    = (double*)(ws + 68559104);

    hipLaunchKernelGGL(k_init, dim3(128), dim3(256), 0, stream,
                       (unsigned*)rowmin, (unsigned*)maxm, bar, acc);
    hipLaunchKernelGGL(k_norms, dim3(16384), dim3(256), 0, stream, x1, x2, sq1, sq2);
    hipLaunchKernelGGL(k_gemm, dim3(8, 8, 64), dim3(16, 16), 0, stream,
                       x1, x2, sq1, sq2, M, (unsigned*)rowmin, (unsigned*)maxm);
    hipLaunchKernelGGL(k_sink, dim3(256), dim3(512), 0, stream,
                       M, rowmin, maxm, part, bar, acc);
    hipLaunchKernelGGL(k_final, dim3(1), dim3(1), 0, stream, acc, out);
}

// Round 6
// 1061.411 us; speedup vs baseline: 3.1242x; 1.0764x over previous
//
#include <hip/hip_runtime.h>
#include <math.h>

#define Bsz 64
#define Nn  512
#define Dd  128
#define NITER 100
#define SLICES 4
#define ROWS 128   // Nn/SLICES

// ---------------- ws layout (bytes) ----------------
// M       : [64][512][512] f32 @ 0          (67108864)
// partials: [64][2][4][512] f32 @ 67108864  (1048576)   parity-double-buffered
// bar     : [64][32] u32 @ 68157440         (8192)
// sq1     : [64][512] f32 @ 68165632
// sq2     : [64][512] f32 @ 68296704
// rowmin  : [64][512] f32-bits @ 68427776
// maxm    : [64] f32-bits @ 68558848
// acc     : double @ 68559104

__device__ inline float blo(unsigned x) { return __uint_as_float(x << 16); }
__device__ inline float bhi(unsigned x) { return __uint_as_float(x & 0xffff0000u); }
__device__ inline unsigned short bf16rne(float f) {
    unsigned u = __float_as_uint(f);
    u += 0x7fffu + ((u >> 16) & 1u);
    return (unsigned short)(u >> 16);
}

// ---------------- init ----------------
__global__ void k_init(unsigned* __restrict__ rowmin, unsigned* __restrict__ maxm,
                       unsigned* __restrict__ bar, double* __restrict__ acc) {
    int t = blockIdx.x * blockDim.x + threadIdx.x;
    if (t < Bsz * Nn) rowmin[t] = 0x7F800000u;  // +inf
    if (t < Bsz) maxm[t] = 0u;
    if (t < Bsz * 32) bar[t] = 0u;
    if (t == 0) *acc = 0.0;
}

// ---------------- row squared norms ----------------
__global__ void k_norms(const float* __restrict__ x1, const float* __restrict__ x2,
                        float* __restrict__ sq1, float* __restrict__ sq2) {
    int gw = (blockIdx.x * blockDim.x + threadIdx.x) >> 6;
    int l = threadIdx.x & 63;
    bool first = gw < Bsz * Nn;
    int row = first ? gw : gw - Bsz * Nn;
    const float* src = first ? x1 : x2;
    float a = src[(size_t)row * Dd + l];
    float c = src[(size_t)row * Dd + 64 + l];
    float s = a * a + c * c;
    #pragma unroll
    for (int m = 32; m >= 1; m >>= 1) s += __shfl_xor(s, m);
    if (l == 0) (first ? sq1 : sq2)[row] = s;
}

// ---------------- M = pairwise distances + per-row min + per-batch max ----------------
__global__ __launch_bounds__(256) void k_gemm(
        const float* __restrict__ x1, const float* __restrict__ x2,
        const float* __restrict__ sq1, const float* __restrict__ sq2,
        float* __restrict__ M, unsigned* __restrict__ rowmin,
        unsigned* __restrict__ maxm) {
    __shared__ float As[64][129];
    __shared__ float Bs[64][129];
    __shared__ float redmin[64][16];
    __shared__ float wmax[4];
    const int b = blockIdx.z;
    const int i0 = blockIdx.y * 64, j0 = blockIdx.x * 64;
    const int tx = threadIdx.x, ty = threadIdx.y;
    const int tid = ty * 16 + tx;

    const float4* a4 = (const float4*)(x1 + ((size_t)b * Nn + i0) * Dd);
    const float4* b4 = (const float4*)(x2 + ((size_t)b * Nn + j0) * Dd);
    #pragma unroll
    for (int e = 0; e < 8; e++) {
        int idx = tid + e * 256;
        int r = idx >> 5, c = idx & 31;
        float4 va = a4[(size_t)r * 32 + c];
        float4 vb = b4[(size_t)r * 32 + c];
        As[r][c*4+0] = va.x; As[r][c*4+1] = va.y; As[r][c*4+2] = va.z; As[r][c*4+3] = va.w;
        Bs[r][c*4+0] = vb.x; Bs[r][c*4+1] = vb.y; Bs[r][c*4+2] = vb.z; Bs[r][c*4+3] = vb.w;
    }
    __syncthreads();

    float acc[4][4] = {{0.0f}};
    for (int k = 0; k < Dd; k++) {
        float av[4], bv[4];
        #pragma unroll
        for (int e = 0; e < 4; e++) av[e] = As[ty*4+e][k];
        #pragma unroll
        for (int f = 0; f < 4; f++) bv[f] = Bs[tx*4+f][k];
        #pragma unroll
        for (int e = 0; e < 4; e++)
            #pragma unroll
            for (int f = 0; f < 4; f++)
                acc[e][f] += av[e] * bv[f];
    }

    float lmax = 0.0f;
    #pragma unroll
    for (int e = 0; e < 4; e++) {
        const int i = i0 + ty*4 + e;
        const float s1 = sq1[b*Nn + i];
        float lmin = 3.0e38f;
        float mvv[4];
        #pragma unroll
        for (int f = 0; f < 4; f++) {
            const int j = j0 + tx*4 + f;
            float d2 = s1 + sq2[b*Nn + j] - 2.0f * acc[e][f];
            float m = sqrtf(fmaxf(d2, 0.0f));
            mvv[f] = m;
            lmin = fminf(lmin, m);
            lmax = fmaxf(lmax, m);
        }
        float4 mv; mv.x = mvv[0]; mv.y = mvv[1]; mv.z = mvv[2]; mv.w = mvv[3];
        *(float4*)(M + ((size_t)b * Nn + i) * Nn + j0 + tx*4) = mv;
        redmin[ty*4+e][tx] = lmin;
    }
    #pragma unroll
    for (int m = 32; m >= 1; m >>= 1) lmax = fmaxf(lmax, __shfl_xor(lmax, m));
    if ((tid & 63) == 0) wmax[tid >> 6] = lmax;
    __syncthreads();
    if (tid < 64) {
        float mn = redmin[tid][0];
        #pragma unroll
        for (int q = 1; q < 16; q++) mn = fminf(mn, redmin[tid][q]);
        atomicMin(&rowmin[b*Nn + i0 + tid], __float_as_uint(mn));
    }
    if (tid == 0) {
        float mm = fmaxf(fmaxf(wmax[0], wmax[1]), fmaxf(wmax[2], wmax[3]));
        atomicMax(&maxm[b], __float_as_uint(mm));
    }
}

// KV row-dot over a 32-col wave slice; Ks layout is XOR-swizzled: byte ^= (row&7)<<4
__device__ inline float kv_rowdot(const char* KsB, int row, int w, const float4* vv) {
    const int swz = (row & 7) << 4;
    float d = 0.f;
    #pragma unroll
    for (int k = 0; k < 4; ++k) {
        const uint4 kb = *(const uint4*)(KsB + row * 1024 + ((w * 64 + k * 16) ^ swz));
        const float4 va = vv[2 * k], vb4 = vv[2 * k + 1];
        d += blo(kb.x) * va.x  + bhi(kb.x) * va.y  + blo(kb.y) * va.z  + bhi(kb.y) * va.w
           + blo(kb.z) * vb4.x + bhi(kb.z) * vb4.y + blo(kb.w) * vb4.z + bhi(kb.w) * vb4.w;
    }
    return d;
}

// ---------------- persistent Sinkhorn: 4 blocks/batch, 1024 thr, shuffle-free loop ----------------
__global__ __launch_bounds__(1024, 4) void k_sink(
        const float* __restrict__ Mg, const float* __restrict__ rowmin_f,
        const float* __restrict__ maxm, float* __restrict__ partials,
        unsigned* __restrict__ bar, double* __restrict__ acc) {
    __shared__ __align__(16) unsigned short Ks[ROWS * Nn];  // 131072 B, bf16, swizzled
    __shared__ float red[16][256];                          // 16384 B  (KtU partials)
    __shared__ float redKV[16][128];                        // 8192 B   (KV partials)
    __shared__ float vsh[Nn];                               // 2048 B
    __shared__ float ush[ROWS];                             // 512 B
    __shared__ float rml[ROWS];                             // 512 B
    __shared__ float sred[16];
    __shared__ double dred[16];
    __shared__ float rminsh;

    const int blk = blockIdx.x;
    const int b  = blk >> 2;
    const int sl = blk & 3;
    const int r0 = sl * ROWS;
    const int t  = threadIdx.x;          // 0..1023
    const int w  = t >> 6, l = t & 63;
    const char* KsB = (const char*)Ks;
    char* KsBw = (char*)Ks;
    const float* __restrict__ Mb = Mg + ((size_t)b * Nn + r0) * Nn;
    const float sc = 1.0f / (0.01f * maxm[b]);
    const float inv512 = 1.0f / 512.0f;
    float* part = partials + (size_t)b * (2 * SLICES * Nn);
    unsigned* mybar = bar + b * 32;

    // batch-wide min of rowmin + local slice rowmin to LDS
    const float rv = rowmin_f[b * Nn + (t & 511)];
    if (t < ROWS) rml[t] = rowmin_f[b * Nn + r0 + t];
    float rm = rv;
    #pragma unroll
    for (int m = 32; m >= 1; m >>= 1) rm = fminf(rm, __shfl_xor(rm, m));
    if (l == 0) sred[w] = rm;
    __syncthreads();
    if (t == 0) {
        float q = sred[0];
        #pragma unroll
        for (int i = 1; i < 16; i++) q = fminf(q, sred[i]);
        rminsh = q;
    }
    __syncthreads();
    if (t < ROWS) ush[t] = __expf(-(rml[t] - rminsh) * sc) * inv512;

    // fill Ks (swizzled) = bf16(exp(-(M - rowmin_row)*sc))
    for (int e = 0; e < 16; ++e) {
        int chunk = e * 1024 + t;            // 16384 8B-chunks
        int row = chunk >> 7;
        int c8  = chunk & 127;               // 8B unit within row
        float4 m4 = *(const float4*)(Mb + (size_t)row * Nn + c8 * 4);
        float rmr = rml[row];
        ushort4 pk;
        pk.x = bf16rne(__expf(-(m4.x - rmr) * sc));
        pk.y = bf16rne(__expf(-(m4.y - rmr) * sc));
        pk.z = bf16rne(__expf(-(m4.z - rmr) * sc));
        pk.w = bf16rne(__expf(-(m4.w - rmr) * sc));
        *(ushort4*)(KsBw + row * 1024 + ((c8 * 8) ^ ((row & 7) << 4))) = pk;
    }
    __syncthreads();

    const int hw = w >> 3;                   // KtU column half
    const int rw = w & 7;                    // KtU row residue
    const int swzw = rw << 4;
    const int cb = hw * 512 + l * 8;         // KtU per-lane col byte

    int par = 0;
    for (int it = 0; it < NITER; ++it) {
        // ---- KtU: wave w -> rows rw+8k, col-half hw; lane: 4 cols (uint2)
        float a0 = 0, a1 = 0, a2 = 0, a3 = 0;
        #pragma unroll
        for (int k = 0; k < 16; ++k) {
            const int r = rw + 8 * k;
            const float ui = ush[r];
            const uint2 kb = *(const uint2*)(KsB + r * 1024 + (cb ^ swzw));
            a0 += blo(kb.x) * ui; a1 += bhi(kb.x) * ui;
            a2 += blo(kb.y) * ui; a3 += bhi(kb.y) * ui;
        }
        *(float4*)&red[w][l * 4] = make_float4(a0, a1, a2, a3);
        __syncthreads();
        if (t < 512) {
            const int j = t;
            const float* rbase = (j < 256) ? &red[0][j] : &red[8][j - 256];
            float cs = 0.f;
            #pragma unroll
            for (int q = 0; q < 8; ++q) cs += rbase[q * 256];
            __hip_atomic_store(&part[par * (SLICES * Nn) + sl * Nn + j], cs,
                               __ATOMIC_RELAXED, __HIP_MEMORY_SCOPE_AGENT);
        }
        __syncthreads();  // drains vmcnt: partial stores complete before signal
        if (t == 0) {
            __hip_atomic_fetch_add(mybar, 1u, __ATOMIC_ACQ_REL, __HIP_MEMORY_SCOPE_AGENT);
            const unsigned tgt = (unsigned)(SLICES * (it + 1));
            while (__hip_atomic_load(mybar, __ATOMIC_ACQUIRE, __HIP_MEMORY_SCOPE_AGENT) < tgt)
                __builtin_amdgcn_s_sleep(1);
        }
        __syncthreads();
        if (t < 512) {
            const float* pp = part + par * (SLICES * Nn);
            float s0 = __hip_atomic_load(&pp[0*Nn + t], __ATOMIC_RELAXED, __HIP_MEMORY_SCOPE_AGENT);
            float s1 = __hip_atomic_load(&pp[1*Nn + t], __ATOMIC_RELAXED, __HIP_MEMORY_SCOPE_AGENT);
            float s2 = __hip_atomic_load(&pp[2*Nn + t], __ATOMIC_RELAXED, __HIP_MEMORY_SCOPE_AGENT);
            float s3 = __hip_atomic_load(&pp[3*Nn + t], __ATOMIC_RELAXED, __HIP_MEMORY_SCOPE_AGENT);
            vsh[t] = inv512 / (s0 + s1 + s2 + s3);
        }
        __syncthreads();
        // ---- KV: wave w -> cols [w*32, w*32+32); lane: rows l and 64+l
        {
            float4 vv[8];
            #pragma unroll
            for (int q = 0; q < 8; ++q) vv[q] = *(const float4*)&vsh[w * 32 + q * 4];
            const float d0 = kv_rowdot(KsB, l, w, vv);
            const float d1 = kv_rowdot(KsB, 64 + l, w, vv);
            redKV[w][l] = d0;
            redKV[w][64 + l] = d1;
        }
        __syncthreads();
        if (t < ROWS) {
            float s = 0.f;
            #pragma unroll
            for (int q = 0; q < 16; ++q) s += redKV[q][t];
            ush[t] = inv512 / s;
        }
        __syncthreads();
        par ^= 1;
    }

    // ---- cost: sum over local rows of u_i * sum_j M_ij K'_ij v_j  (KtU-style layout)
    double lacc = 0.0;
    {
        const float4 vq = *(const float4*)&vsh[hw * 256 + l * 4];
        for (int k = 0; k < 16; ++k) {
            const int r = rw + 8 * k;
            const uint2 kb = *(const uint2*)(KsB + r * 1024 + (cb ^ swzw));
            const float4 mq = *(const float4*)(Mb + (size_t)r * Nn + hw * 256 + l * 4);
            float p = mq.x * blo(kb.x) * vq.x + mq.y * bhi(kb.x) * vq.y
                    + mq.z * blo(kb.y) * vq.z + mq.w * bhi(kb.y) * vq.w;
            lacc += (double)(p * ush[r]);
        }
    }
    #pragma unroll
    for (int m = 32; m >= 1; m >>= 1) lacc += __shfl_xor(lacc, m);
    if (l == 0) dred[w] = lacc;
    __syncthreads();
    if (t == 0) {
        double tot = 0.0;
        #pragma unroll
        for (int q = 0; q < 16; ++q) tot += dred[q];
        atomicAdd(acc, tot);
    }
}

__global__ void k_final(const double* __restrict__ acc, float* __restrict__ out) {
    out[0] = (float)acc[0];
}

extern "C" void kernel_launch(void* const* d_in, const int* in_sizes, int n_in,
                              void* d_out, int out_size, void* d_ws, size_t ws_size,
                              hipStream_t stream) {
    const float* x1 = (const float*)d_in[0];
    const float* x2 = (const float*)d_in[1];
    float* out = (float*)d_out;
    char* ws = (char*)d_ws;

    float*    M      = (float*)(ws);
    float*    part   = (float*)(ws + 67108864);
    unsigned* bar    = (unsigned*)(ws + 68157440);
    float*    sq1    = (float*)(ws + 68165632);
    float*    sq2    = (float*)(ws + 68296704);
    float*    rowmin = (float*)(ws + 68427776);
    float*    maxm   = (float*)(ws + 68558848);
    double*   acc    = (double*)(ws + 68559104);

    hipLaunchKernelGGL(k_init, dim3(128), dim3(256), 0, stream,
                       (unsigned*)rowmin, (unsigned*)maxm, bar, acc);
    hipLaunchKernelGGL(k_norms, dim3(16384), dim3(256), 0, stream, x1, x2, sq1, sq2);
    hipLaunchKernelGGL(k_gemm, dim3(8, 8, 64), dim3(16, 16), 0, stream,
                       x1, x2, sq1, sq2, M, (unsigned*)rowmin, (unsigned*)maxm);
    hipLaunchKernelGGL(k_sink, dim3(256), dim3(1024), 0, stream,
                       M, rowmin, maxm, part, bar, acc);
    hipLaunchKernelGGL(k_final, dim3(1), dim3(1), 0, stream, acc, out);
}